// Round 8
// baseline (96.226 us; speedup 1.0000x reference)
//
#include <hip/hip_runtime.h>

typedef short  bf16x8 __attribute__((ext_vector_type(8)));
typedef float  f32x16 __attribute__((ext_vector_type(16)));

#define JS      8            // j-splits (grid.y)
#define STREAMS (JS * 4)     // wave-streams per i-tile (stride in j-tiles)
#define JTPAD   STREAMS      // extra packed j-tiles => branchless prefetch
#define TI      128          // i-points per block (4 MFMAs per A-load)

__device__ __forceinline__ unsigned short f2bf(float x) {
    unsigned u = __builtin_bit_cast(unsigned, x);
    u += 0x7FFF + ((u >> 16) & 1);          // RNE
    return (unsigned short)(u >> 16);
}
__device__ __forceinline__ float bf2f(unsigned short h) {
    unsigned u = ((unsigned)h) << 16;
    return __builtin_bit_cast(float, u);
}

// ---- pack padding points into MFMA-A planes + zero the output ----
// Row j (K=16 bf16): k0-2 qh | k3-5 ql | k6-8 qh | k9-11 ql | k12-13 negc h/l | 0,0
// plane0 = k0-7 (lanes 0-31), plane1 = k8-15 (lanes 32-63).
__global__ __launch_bounds__(256) void dens_pack_kernel(
    const float* __restrict__ pad, uint4* __restrict__ ws,
    int* __restrict__ out, int M, int mtot, int N)
{
    const int j = blockIdx.x * 256 + threadIdx.x;
    if (j < N) out[j] = 0;                      // fold output zeroing here
    if (j >= mtot) return;

    float qx = 0.f, qy = 0.f, qz = 0.f;
    float negc = -1.0e6f;                       // padded rows never match
    if (j < M) {
        qx = pad[3 * j]; qy = pad[3 * j + 1]; qz = pad[3 * j + 2];
        negc = 0.125f - 0.5f * (qx * qx + qy * qy + qz * qz);   // (r^2 - |q|^2)/2
    }
    const unsigned short xh = f2bf(qx), yh = f2bf(qy), zh = f2bf(qz);
    const unsigned short xl = f2bf(qx - bf2f(xh));
    const unsigned short yl = f2bf(qy - bf2f(yh));
    const unsigned short zl = f2bf(qz - bf2f(zh));
    const unsigned short ch = f2bf(negc);
    const unsigned short cl = f2bf(negc - bf2f(ch));

    uint4 p0, p1;
    p0.x = (unsigned)xh | ((unsigned)yh << 16);   // k0,k1
    p0.y = (unsigned)zh | ((unsigned)xl << 16);   // k2,k3
    p0.z = (unsigned)yl | ((unsigned)zl << 16);   // k4,k5
    p0.w = (unsigned)xh | ((unsigned)yh << 16);   // k6,k7
    p1.x = (unsigned)zh | ((unsigned)xl << 16);   // k8,k9
    p1.y = (unsigned)yl | ((unsigned)zl << 16);   // k10,k11
    p1.z = (unsigned)ch | ((unsigned)cl << 16);   // k12,k13
    p1.w = 0;                                     // k14,k15
    ws[j]        = p0;                            // plane0
    ws[mtot + j] = p1;                            // plane1
}

__device__ __forceinline__ void make_bfrag(const float* __restrict__ pc,
                                           int i, int N, int half,
                                           bf16x8& B, float& ha)
{
    float px = 0.f, py = 0.f, pz = 0.f;
    ha = 3.0e38f;                                // i-pad: s >= 3e38 never true
    if (i < N) {
        px = pc[3 * i]; py = pc[3 * i + 1]; pz = pc[3 * i + 2];
        ha = 0.5f * (px * px + py * py + pz * pz);   // |p|^2/2, fp32
    }
    const short xh = (short)f2bf(px), yh = (short)f2bf(py), zh = (short)f2bf(pz);
    const short xl = (short)f2bf(px - bf2f((unsigned short)xh));
    const short yl = (short)f2bf(py - bf2f((unsigned short)yh));
    const short zl = (short)f2bf(pz - bf2f((unsigned short)zh));
    const short ONE = (short)0x3F80;
    const bf16x8 B0 = {xh, yh, zh, xh, yh, zh, xl, yl};   // k0-7
    const bf16x8 B1 = {zl, xl, yl, zl, ONE, ONE, 0, 0};   // k8-15
    B = half ? B1 : B0;
}

// grid (157 x JS), 256 thr. 128-wide i-tile; STREAMS wave-streams stride j-tiles.
// Per j-tile: 1 dwordx4 A-load (L2-hit) -> 4 raw-asm MFMAs with "=&v" dests
// (ArchVGPRs: no AGPR round-trip, no C re-zero), then cmp+addc count.
// Hazards: s_nop 1 leading (VALU->MFMA src), 3 trailing MFMAs + 2x s_nop 7
// cover MFMA->VALU-read (~18 cyc) for the first-consumed D.
__global__ __launch_bounds__(256, 2) void dens_mfma_kernel(
    const float* __restrict__ pc,     // [N,3] pointcloud
    const char*  __restrict__ wsA,    // packed A planes (jt+JTPAD tiles)
    int* __restrict__ out,            // [N] counts (pre-zeroed)
    int N, int jt, int p1off)
{
    const int lane = threadIdx.x & 63;
    const int w    = threadIdx.x >> 6;   // wave 0..3
    const int n    = lane & 31;          // output col within 32-tile = i
    const int half = lane >> 5;          // k-chunk 0/1

    const int ibase = blockIdx.x * TI;
    bf16x8 B0, B1, B2, B3; float ha0, ha1, ha2, ha3;
    make_bfrag(pc, ibase + n,      N, half, B0, ha0);
    make_bfrag(pc, ibase + 32 + n, N, half, B1, ha1);
    make_bfrag(pc, ibase + 64 + n, N, half, B2, ha2);
    make_bfrag(pc, ibase + 96 + n, N, half, B3, ha3);

    const int stream = blockIdx.y * 4 + w;          // 0..STREAMS-1
    const char* aptr = wsA + (half ? p1off : 0) + n * 16 + (size_t)stream * 512;

    f32x16 Z = {0.f};                               // zero C, materialized once
    int c0 = 0, c1 = 0, c2 = 0, c3 = 0;

    bf16x8 A = *(const bf16x8*)aptr;                // tile `stream`

    for (int t = stream; t < jt; t += STREAMS) {
        const bf16x8 An = *(const bf16x8*)(aptr + STREAMS * 512);  // pad-safe
        f32x16 s0, s1, s2, s3;
        asm("s_nop 1\n\t"
            "v_mfma_f32_32x32x16_bf16 %0, %4, %5, %9\n\t"
            "v_mfma_f32_32x32x16_bf16 %1, %4, %6, %9\n\t"
            "v_mfma_f32_32x32x16_bf16 %2, %4, %7, %9\n\t"
            "v_mfma_f32_32x32x16_bf16 %3, %4, %8, %9\n\t"
            "s_nop 7\n\t"
            "s_nop 7"
            : "=&v"(s0), "=&v"(s1), "=&v"(s2), "=&v"(s3)
            : "v"(A), "v"(B0), "v"(B1), "v"(B2), "v"(B3), "v"(Z));
        #pragma unroll
        for (int r = 0; r < 16; ++r) c0 += (s0[r] >= ha0);
        #pragma unroll
        for (int r = 0; r < 16; ++r) c1 += (s1[r] >= ha1);
        #pragma unroll
        for (int r = 0; r < 16; ++r) c2 += (s2[r] >= ha2);
        #pragma unroll
        for (int r = 0; r < 16; ++r) c3 += (s3[r] >= ha3);
        A = An;
        aptr += STREAMS * 512;
    }

    // col n lives in lanes n and n+32 (complementary row halves)
    int g0 = c0 + __shfl_xor(c0, 32);
    int g1 = c1 + __shfl_xor(c1, 32);
    int g2 = c2 + __shfl_xor(c2, 32);
    int g3 = c3 + __shfl_xor(c3, 32);

    __shared__ int red[4][TI];
    if (lane < 32) {
        red[w][n]      = g0;
        red[w][n + 32] = g1;
        red[w][n + 64] = g2;
        red[w][n + 96] = g3;
    }
    __syncthreads();
    if (threadIdx.x < TI) {
        const int ii = ibase + threadIdx.x;
        if (ii < N) {
            const int s = red[0][threadIdx.x] + red[1][threadIdx.x] +
                          red[2][threadIdx.x] + red[3][threadIdx.x];
            atomicAdd(&out[ii], s);
        }
    }
}

extern "C" void kernel_launch(void* const* d_in, const int* in_sizes, int n_in,
                              void* d_out, int out_size, void* d_ws, size_t ws_size,
                              hipStream_t stream) {
    const float* pc  = (const float*)d_in[0];   // [N,3] pointcloud
    const float* pad = (const float*)d_in[1];   // [M,3] pointcloud_padding
    int* out = (int*)d_out;

    const int N = in_sizes[0] / 3;              // 20000
    const int M = in_sizes[1] / 3;              // 25000
    const int jt   = (M + 31) / 32;             // 782 j-tiles
    const int jtp  = jt + JTPAD;                // + pad tiles for prefetch
    const int mtot = jtp * 32;                  // packed rows (~833 KB in ws)

    dens_pack_kernel<<<(mtot + 255) / 256, 256, 0, stream>>>(
        pad, (uint4*)d_ws, out, M, mtot, N);

    dim3 grid((N + TI - 1) / TI, JS);           // 157 x 8
    dens_mfma_kernel<<<grid, 256, 0, stream>>>(
        pc, (const char*)d_ws, out, N, jt, mtot * 16);
}

// Round 9
// 91.854 us; speedup vs baseline: 1.0476x; 1.0476x over previous
//
#include <hip/hip_runtime.h>

typedef short  bf16x8 __attribute__((ext_vector_type(8)));

#define JS      8            // j-splits (grid.y)
#define STREAMS (JS * 4)     // wave-streams per i-tile (stride in j-tiles)
#define TI      128          // i-points per block (4 MFMA groups)

__device__ __forceinline__ unsigned short f2bf(float x) {
    unsigned u = __builtin_bit_cast(unsigned, x);
    u += 0x7FFF + ((u >> 16) & 1);          // RNE
    return (unsigned short)(u >> 16);
}
__device__ __forceinline__ float bf2f(unsigned short h) {
    unsigned u = ((unsigned)h) << 16;
    return __builtin_bit_cast(float, u);
}

// ---- pack padding points into MFMA-A planes + zero the output ----
// Row j (K=16 bf16): k0-2 qh | k3-5 ql | k6-8 qh | k9-11 ql | k12-13 negc h/l | 0,0
// plane0 = k0-7 (lanes 0-31), plane1 = k8-15 (lanes 32-63).
__global__ __launch_bounds__(256) void dens_pack_kernel(
    const float* __restrict__ pad, uint4* __restrict__ ws,
    int* __restrict__ out, int M, int mtot, int N)
{
    const int j = blockIdx.x * 256 + threadIdx.x;
    if (j < N) out[j] = 0;                      // fold output zeroing here
    if (j >= mtot) return;

    float qx = 0.f, qy = 0.f, qz = 0.f;
    float negc = -1.0e6f;                       // padded rows never match
    if (j < M) {
        qx = pad[3 * j]; qy = pad[3 * j + 1]; qz = pad[3 * j + 2];
        negc = 0.125f - 0.5f * (qx * qx + qy * qy + qz * qz);   // (r^2 - |q|^2)/2
    }
    const unsigned short xh = f2bf(qx), yh = f2bf(qy), zh = f2bf(qz);
    const unsigned short xl = f2bf(qx - bf2f(xh));
    const unsigned short yl = f2bf(qy - bf2f(yh));
    const unsigned short zl = f2bf(qz - bf2f(zh));
    const unsigned short ch = f2bf(negc);
    const unsigned short cl = f2bf(negc - bf2f(ch));

    uint4 p0, p1;
    p0.x = (unsigned)xh | ((unsigned)yh << 16);   // k0,k1
    p0.y = (unsigned)zh | ((unsigned)xl << 16);   // k2,k3
    p0.z = (unsigned)yl | ((unsigned)zl << 16);   // k4,k5
    p0.w = (unsigned)xh | ((unsigned)yh << 16);   // k6,k7
    p1.x = (unsigned)zh | ((unsigned)xl << 16);   // k8,k9
    p1.y = (unsigned)yl | ((unsigned)zl << 16);   // k10,k11
    p1.z = (unsigned)ch | ((unsigned)cl << 16);   // k12,k13
    p1.w = 0;                                     // k14,k15
    ws[j]        = p0;                            // plane0
    ws[mtot + j] = p1;                            // plane1
}

__device__ __forceinline__ void make_bfrag(const float* __restrict__ pc,
                                           int i, int N, int half,
                                           bf16x8& B, float& ha)
{
    float px = 0.f, py = 0.f, pz = 0.f;
    ha = 3.0e38f;                                // i-pad: s >= 3e38 never true
    if (i < N) {
        px = pc[3 * i]; py = pc[3 * i + 1]; pz = pc[3 * i + 2];
        ha = 0.5f * (px * px + py * py + pz * pz);   // |p|^2/2, fp32
    }
    const short xh = (short)f2bf(px), yh = (short)f2bf(py), zh = (short)f2bf(pz);
    const short xl = (short)f2bf(px - bf2f((unsigned short)xh));
    const short yl = (short)f2bf(py - bf2f((unsigned short)yh));
    const short zl = (short)f2bf(pz - bf2f((unsigned short)zh));
    const short ONE = (short)0x3F80;
    const bf16x8 B0 = {xh, yh, zh, xh, yh, zh, xl, yl};   // k0-7
    const bf16x8 B1 = {zl, xl, yl, zl, ONE, ONE, 0, 0};   // k8-15
    B = half ? B1 : B0;
}

// one cmp+count pair: c += (s >= ha), via vcc carry-in add
#define CONSUME(R, HA, CC) \
    "v_cmp_le_f32 vcc, " HA ", " R "\n\t" \
    "v_addc_co_u32 " CC ", vcc, 0, " CC ", vcc\n\t"
#define CONS4(R0, R1, R2, R3, HA, CC) \
    CONSUME(R0, HA, CC) CONSUME(R1, HA, CC) CONSUME(R2, HA, CC) CONSUME(R3, HA, CC)

// grid (157 x JS), 256 thr. 128-wide i-tile; 32 wave-streams stride j-tiles.
// Entire K-loop is ONE asm block with hard-coded physical VGPRs:
//   d0=v[32:47] d1=v[48:63] Z=v[64:79] A=v[80:83] An=v[84:87] addr=v[88:89]
// Per visit: 1 dwordx4 prefetch, 4 MFMAs (2 D-buffers, WAR-safe in-order),
// 128 cmp/addc, ~9 overhead instrs. No AGPR traffic possible.
__global__ __launch_bounds__(256, 2) void dens_mfma_kernel(
    const float* __restrict__ pc,     // [N,3] pointcloud
    const char*  __restrict__ wsA,    // packed A planes ((visits+1)*STREAMS tiles)
    int* __restrict__ out,            // [N] counts (pre-zeroed)
    int N, int jt, int p1off)
{
    const int lane = threadIdx.x & 63;
    const int w    = threadIdx.x >> 6;   // wave 0..3
    const int n    = lane & 31;          // output col within 32-tile = i
    const int half = lane >> 5;          // k-chunk 0/1

    const int ibase = blockIdx.x * TI;
    bf16x8 B0, B1, B2, B3; float ha0, ha1, ha2, ha3;
    make_bfrag(pc, ibase + n,      N, half, B0, ha0);
    make_bfrag(pc, ibase + 32 + n, N, half, B1, ha1);
    make_bfrag(pc, ibase + 64 + n, N, half, B2, ha2);
    make_bfrag(pc, ibase + 96 + n, N, half, B3, ha3);

    const int stream = blockIdx.y * 4 + w;          // 0..STREAMS-1
    const unsigned long long a0 =
        (unsigned long long)(wsA + (half ? p1off : 0) + n * 16 + (size_t)stream * 512);
    const unsigned alo = (unsigned)a0;
    const unsigned ahi = (unsigned)(a0 >> 32);

    int visits = (jt + STREAMS - 1) / STREAMS;      // uniform (pads never count)
    int c0 = 0, c1 = 0, c2 = 0, c3 = 0;

    asm volatile(
        // ---- preamble: addr, Z=0, first prefetch ----
        "v_mov_b32 v88, %13\n\t"
        "v_mov_b32 v89, %14\n\t"
        "v_mov_b32 v64, 0\n\t" "v_mov_b32 v65, 0\n\t"
        "v_mov_b32 v66, 0\n\t" "v_mov_b32 v67, 0\n\t"
        "v_mov_b32 v68, 0\n\t" "v_mov_b32 v69, 0\n\t"
        "v_mov_b32 v70, 0\n\t" "v_mov_b32 v71, 0\n\t"
        "v_mov_b32 v72, 0\n\t" "v_mov_b32 v73, 0\n\t"
        "v_mov_b32 v74, 0\n\t" "v_mov_b32 v75, 0\n\t"
        "v_mov_b32 v76, 0\n\t" "v_mov_b32 v77, 0\n\t"
        "v_mov_b32 v78, 0\n\t" "v_mov_b32 v79, 0\n\t"
        "global_load_dwordx4 v[84:87], v[88:89], off\n\t"
        "v_add_co_u32 v88, vcc, 0x4000, v88\n\t"
        "v_addc_co_u32 v89, vcc, 0, v89, vcc\n\t"
        "Ldens%=:\n\t"
        "s_waitcnt vmcnt(0)\n\t"
        "v_mov_b32 v80, v84\n\t"
        "v_mov_b32 v81, v85\n\t"
        "v_mov_b32 v82, v86\n\t"
        "v_mov_b32 v83, v87\n\t"
        "global_load_dwordx4 v[84:87], v[88:89], off\n\t"
        "v_add_co_u32 v88, vcc, 0x4000, v88\n\t"
        "v_addc_co_u32 v89, vcc, 0, v89, vcc\n\t"
        "v_mfma_f32_32x32x16_bf16 v[32:47], v[80:83], %5, v[64:79]\n\t"
        "v_mfma_f32_32x32x16_bf16 v[48:63], v[80:83], %6, v[64:79]\n\t"
        "s_nop 7\n\t"
        "s_nop 2\n\t"
        // consume d0 -> c0 (group 0)
        CONS4("v32","v33","v34","v35","%9","%0")
        CONS4("v36","v37","v38","v39","%9","%0")
        CONS4("v40","v41","v42","v43","%9","%0")
        CONS4("v44","v45","v46","v47","%9","%0")
        "v_mfma_f32_32x32x16_bf16 v[32:47], v[80:83], %7, v[64:79]\n\t"
        // consume d1 -> c1 (group 1)
        CONS4("v48","v49","v50","v51","%10","%1")
        CONS4("v52","v53","v54","v55","%10","%1")
        CONS4("v56","v57","v58","v59","%10","%1")
        CONS4("v60","v61","v62","v63","%10","%1")
        "v_mfma_f32_32x32x16_bf16 v[48:63], v[80:83], %8, v[64:79]\n\t"
        // consume d0 -> c2 (group 2)
        CONS4("v32","v33","v34","v35","%11","%2")
        CONS4("v36","v37","v38","v39","%11","%2")
        CONS4("v40","v41","v42","v43","%11","%2")
        CONS4("v44","v45","v46","v47","%11","%2")
        // consume d1 -> c3 (group 3)
        CONS4("v48","v49","v50","v51","%12","%3")
        CONS4("v52","v53","v54","v55","%12","%3")
        CONS4("v56","v57","v58","v59","%12","%3")
        CONS4("v60","v61","v62","v63","%12","%3")
        "s_sub_u32 %4, %4, 1\n\t"
        "s_cmp_lg_u32 %4, 0\n\t"
        "s_cbranch_scc1 Ldens%=\n\t"
        : "+v"(c0), "+v"(c1), "+v"(c2), "+v"(c3), "+s"(visits)
        : "v"(B0), "v"(B1), "v"(B2), "v"(B3),
          "v"(ha0), "v"(ha1), "v"(ha2), "v"(ha3),
          "v"(alo), "v"(ahi)
        : "vcc", "scc", "memory",
          "v32","v33","v34","v35","v36","v37","v38","v39",
          "v40","v41","v42","v43","v44","v45","v46","v47",
          "v48","v49","v50","v51","v52","v53","v54","v55",
          "v56","v57","v58","v59","v60","v61","v62","v63",
          "v64","v65","v66","v67","v68","v69","v70","v71",
          "v72","v73","v74","v75","v76","v77","v78","v79",
          "v80","v81","v82","v83","v84","v85","v86","v87",
          "v88","v89");

    // col n lives in lanes n and n+32 (complementary row halves)
    int g0 = c0 + __shfl_xor(c0, 32);
    int g1 = c1 + __shfl_xor(c1, 32);
    int g2 = c2 + __shfl_xor(c2, 32);
    int g3 = c3 + __shfl_xor(c3, 32);

    __shared__ int red[4][TI];
    if (lane < 32) {
        red[w][n]      = g0;
        red[w][n + 32] = g1;
        red[w][n + 64] = g2;
        red[w][n + 96] = g3;
    }
    __syncthreads();
    if (threadIdx.x < TI) {
        const int ii = ibase + threadIdx.x;
        if (ii < N) {
            const int s = red[0][threadIdx.x] + red[1][threadIdx.x] +
                          red[2][threadIdx.x] + red[3][threadIdx.x];
            atomicAdd(&out[ii], s);
        }
    }
}

extern "C" void kernel_launch(void* const* d_in, const int* in_sizes, int n_in,
                              void* d_out, int out_size, void* d_ws, size_t ws_size,
                              hipStream_t stream) {
    const float* pc  = (const float*)d_in[0];   // [N,3] pointcloud
    const float* pad = (const float*)d_in[1];   // [M,3] pointcloud_padding
    int* out = (int*)d_out;

    const int N = in_sizes[0] / 3;              // 20000
    const int M = in_sizes[1] / 3;              // 25000
    const int jt     = (M + 31) / 32;           // 782 j-tiles
    const int visits = (jt + STREAMS - 1) / STREAMS;   // 25
    const int jtp    = (visits + 1) * STREAMS;  // 832 tiles incl. pad+prefetch
    const int mtot   = jtp * 32;                // 26624 rows (~852 KB in ws)

    dens_pack_kernel<<<(mtot + 255) / 256, 256, 0, stream>>>(
        pad, (uint4*)d_ws, out, M, mtot, N);

    dim3 grid((N + TI - 1) / TI, JS);           // 157 x 8
    dens_mfma_kernel<<<grid, 256, 0, stream>>>(
        pc, (const char*)d_ws, out, N, jt, mtot * 16);
}